// Round 6
// baseline (638.397 us; speedup 1.0000x reference)
//
#include <hip/hip_runtime.h>
#include <hip/hip_bf16.h>
#include <cstdint>

// Problem dims
#define TSEQ 2048
#define NB   2
#define NH   16
#define EDIM 1024
#define DDIM 64
#define VOC  32000
#define MROWS (NB*TSEQ)   // 4096
#define QKVN  (3*EDIM)    // 3072

typedef _Float16 f16x8 __attribute__((ext_vector_type(8)));
typedef float    f32x4 __attribute__((ext_vector_type(4)));
typedef unsigned short u16x4v __attribute__((ext_vector_type(4)));
typedef unsigned short u16x8v __attribute__((ext_vector_type(8)));

__device__ __forceinline__ unsigned short f2h_bits(float v) {
  return __builtin_bit_cast(unsigned short, (_Float16)v);
}

// async global->LDS, 16B per lane. LDS dest is wave-uniform base; lane i
// writes bytes [16*i, 16*i+16). Per-lane global source address is free.
__device__ __forceinline__ void gload_lds16(const void* g, void* l) {
  __builtin_amdgcn_global_load_lds((__attribute__((address_space(1))) void*)(g),
                                   (__attribute__((address_space(3))) void*)(l),
                                   16, 0, 0);
}

// ---------------- embedding: x[row,e] = tok_emb[X[row],e] + pos_emb[row%T,e] (f16 out)
__global__ __launch_bounds__(256) void embed_kernel(
    const int* __restrict__ X, const float* __restrict__ tokE,
    const float* __restrict__ posE, unsigned short* __restrict__ x) {
  int g = blockIdx.x * 256 + threadIdx.x;
  int row = g >> 7;            // 128 threads per row of 1024
  int e8  = (g & 127) * 8;
  int tk  = X[row];
  int tp  = row & (TSEQ - 1);
  const float4* ta = reinterpret_cast<const float4*>(&tokE[(size_t)tk * EDIM + e8]);
  const float4* pa = reinterpret_cast<const float4*>(&posE[(size_t)tp * EDIM + e8]);
  float4 a0 = ta[0], a1 = ta[1], p0 = pa[0], p1 = pa[1];
  u16x8v o;
  o[0] = f2h_bits(a0.x + p0.x); o[1] = f2h_bits(a0.y + p0.y);
  o[2] = f2h_bits(a0.z + p0.z); o[3] = f2h_bits(a0.w + p0.w);
  o[4] = f2h_bits(a1.x + p1.x); o[5] = f2h_bits(a1.y + p1.y);
  o[6] = f2h_bits(a1.z + p1.z); o[7] = f2h_bits(a1.w + p1.w);
  *reinterpret_cast<u16x8v*>(&x[(size_t)row * EDIM + e8]) = o;
}

// ---------------- W{q,k,v}[h,e,d] (f32) -> Wt[n=mat*1024+h*64+d][e] (f16)
__global__ __launch_bounds__(256) void trans_qkvw(
    const float* __restrict__ Wq, const float* __restrict__ Wk,
    const float* __restrict__ Wv, unsigned short* __restrict__ Wt) {
  __shared__ float ts[64][65];
  int bid = blockIdx.x;          // 3*16*16 = 768
  int mat = bid >> 8;
  int h   = (bid >> 4) & 15;
  int et  = bid & 15;
  const float* src = (mat == 0 ? Wq : (mat == 1 ? Wk : Wv)) + (size_t)h * EDIM * DDIM;
  int t = threadIdx.x;
  int rr = t >> 4, c4 = (t & 15) * 4;
#pragma unroll
  for (int p = 0; p < 4; ++p) {
    int r = p * 16 + rr;  // e within tile
    float4 v = *reinterpret_cast<const float4*>(&src[(size_t)(et * 64 + r) * DDIM + c4]);
    ts[r][c4 + 0] = v.x; ts[r][c4 + 1] = v.y; ts[r][c4 + 2] = v.z; ts[r][c4 + 3] = v.w;
  }
  __syncthreads();
#pragma unroll
  for (int p = 0; p < 4; ++p) {
    int dr = p * 16 + rr;  // d
    u16x4v o;
#pragma unroll
    for (int j = 0; j < 4; ++j) o[j] = f2h_bits(ts[c4 + j][dr]);
    *reinterpret_cast<u16x4v*>(&Wt[((size_t)(mat * EDIM + h * 64 + dr)) * EDIM + et * 64 + c4]) = o;
  }
}

// ---------------- lm_W[e,v] (f32) -> lm_Wt[v,e] (f16)
__global__ __launch_bounds__(256) void trans_lmw(
    const float* __restrict__ W, unsigned short* __restrict__ Wt) {
  __shared__ float ts[64][65];
  int bid = blockIdx.x;        // 500 * 16 = 8000
  int vt = bid / 16, et = bid % 16;
  int t = threadIdx.x;
  int rr = t >> 4, c4 = (t & 15) * 4;
#pragma unroll
  for (int p = 0; p < 4; ++p) {
    int r = p * 16 + rr;  // e within tile
    float4 v = *reinterpret_cast<const float4*>(&W[(size_t)(et * 64 + r) * VOC + vt * 64 + c4]);
    ts[r][c4 + 0] = v.x; ts[r][c4 + 1] = v.y; ts[r][c4 + 2] = v.z; ts[r][c4 + 3] = v.w;
  }
  __syncthreads();
#pragma unroll
  for (int p = 0; p < 4; ++p) {
    int vr = p * 16 + rr;  // v within tile
    u16x4v o;
#pragma unroll
    for (int j = 0; j < 4; ++j) o[j] = f2h_bits(ts[c4 + j][vr]);
    *reinterpret_cast<u16x4v*>(&Wt[(size_t)(vt * 64 + vr) * EDIM + et * 64 + c4]) = o;
  }
}

// ---------------- 128x256 GEMM (QKV proj): unchanged from R5 (proven 40us)
template <bool F32OUT, bool BIAS>
__global__ __launch_bounds__(512, 4) void gemm128(
    const unsigned short* __restrict__ A, const unsigned short* __restrict__ Bt,
    float* __restrict__ Cf, unsigned short* __restrict__ Ch,
    const float* __restrict__ bias, int N, int K) {
  __shared__ __align__(16) unsigned short lds[3 * 12288];   // 72 KiB
  const int tid = threadIdx.x;
  const int w = tid >> 6, l = tid & 63;
  const int wr = w >> 2, wc = w & 3;      // 2 x 4 wave grid
  const int l15 = l & 15, lhi = l >> 4;
  const int orig = blockIdx.x;
  const int bx = orig >> 5;           // N-block
  const int by = orig & 31;           // M-block (fastest)
  const int m0 = by * 128, n0 = bx * 256;
  const int swzc = lhi ^ ((l15 >> 1) & 3);
  const int aOff = (wr * 64 + l15) * 32 + swzc * 8;
  const int bOff = 4096 + (wc * 64 + l15) * 32 + swzc * 8;
  const int sr = l >> 2;
  const int sc = (l & 3) ^ ((l >> 3) & 3);
  const unsigned short* PA = A  + (size_t)(m0 + w * 16 + sr) * K + sc * 8;
  const unsigned short* PB = Bt + (size_t)(n0 + w * 16 + sr) * K + sc * 8;
  const int dOff = w * 512;

#define STAGE32(ts, slot) do {                                                \
    gload_lds16(PA + (size_t)(ts) * 32, &lds[(slot) * 12288 + dOff]);         \
    gload_lds16(PB + (size_t)(ts) * 32, &lds[(slot) * 12288 + 4096 + dOff]);  \
    gload_lds16(PB + (size_t)128 * K + (size_t)(ts) * 32,                     \
                &lds[(slot) * 12288 + 8192 + dOff]);                          \
  } while (0)

  f32x4 acc[4][4] = {};
  STAGE32(0, 0);
  STAGE32(1, 1);
  asm volatile("s_waitcnt vmcnt(3)" ::: "memory");
  __builtin_amdgcn_sched_barrier(0);
  __builtin_amdgcn_s_barrier();

  const int NT = K >> 5;
  int slotC = 0;
  for (int t = 0; t < NT; ++t) {
    const int base = slotC * 12288;
    const int ts = (t + 2 < NT) ? (t + 2) : (NT - 1);
    int dslot = slotC + 2; if (dslot >= 3) dslot -= 3;
    STAGE32(ts, dslot);
    f16x8 af[4], bf[4];
#pragma unroll
    for (int q = 0; q < 4; ++q) af[q] = *reinterpret_cast<const f16x8*>(&lds[base + aOff + q * 512]);
#pragma unroll
    for (int q = 0; q < 4; ++q) bf[q] = *reinterpret_cast<const f16x8*>(&lds[base + bOff + q * 512]);
    asm volatile("s_waitcnt lgkmcnt(0)" ::: "memory");
    __builtin_amdgcn_sched_barrier(0);
    __builtin_amdgcn_s_setprio(1);
#pragma unroll
    for (int mi = 0; mi < 4; ++mi)
#pragma unroll
      for (int ni = 0; ni < 4; ++ni)
        acc[mi][ni] = __builtin_amdgcn_mfma_f32_16x16x32_f16(af[mi], bf[ni], acc[mi][ni], 0, 0, 0);
    __builtin_amdgcn_s_setprio(0);
    asm volatile("s_waitcnt vmcnt(3)" ::: "memory");
    __builtin_amdgcn_sched_barrier(0);
    __builtin_amdgcn_s_barrier();
    ++slotC; if (slotC == 3) slotC = 0;
  }
#undef STAGE32
  asm volatile("s_waitcnt vmcnt(0)" ::: "memory");

#pragma unroll
  for (int ni = 0; ni < 4; ++ni) {
    const int col = n0 + wc * 64 + ni * 16 + l15;
    float bv = BIAS ? bias[col] : 0.0f;
#pragma unroll
    for (int mi = 0; mi < 4; ++mi) {
#pragma unroll
      for (int r = 0; r < 4; ++r) {
        const size_t row = (size_t)m0 + wr * 64 + mi * 16 + lhi * 4 + r;
        float v = acc[mi][ni][r] + bv;
        if constexpr (F32OUT) __builtin_nontemporal_store(v, &Cf[row * (size_t)N + col]);
        else                  Ch[row * (size_t)N + col] = f2h_bits(v);
      }
    }
  }
}

// ---------------- 64x256 GEMM (LM head): shrink live B-panel set.
// With BM=64, M has 64 tiles -> the 512 co-resident blocks (2/CU) span only
// 8 B-panels = 4 MB (fits per-XCD L2; trivially L3-held), so B is fetched
// from HBM ~once instead of ~4.7x (R5: FETCH 314 MB, 240 MB of it B-refetch).
// 4 waves (1x4), wave tile 64x64, BK=32. LDS: 3 slots x {A[64][32],B[256][32]}
// = 3 x 20 KB = 60 KB -> 2 blocks/CU. Depth-2 counted pipeline: 5 loads/wave
// per tile (1 A + 4 B), per-tile barrier vmcnt(5) drains t+1, keeps t+2.
// Same chunk-XOR swizzle pair as gemm128 (measured conflicts = 0).
template <bool F32OUT, bool BIAS>
__global__ __launch_bounds__(256, 2) void gemm64(
    const unsigned short* __restrict__ A, const unsigned short* __restrict__ Bt,
    float* __restrict__ Cf, unsigned short* __restrict__ Ch,
    const float* __restrict__ bias, int N, int K) {
  __shared__ __align__(16) unsigned short lds[3 * 10240];   // 60 KiB
  const int tid = threadIdx.x;
  const int w = tid >> 6, l = tid & 63;   // 4 waves; wave n-col = w
  const int l15 = l & 15, lhi = l >> 4;
  const int orig = blockIdx.x;
  const int bx = orig >> 6;           // N-block (125)
  const int by = orig & 63;           // M-block (fastest, 64)
  const int m0 = by * 64, n0 = bx * 256;

  // ds_read swizzled chunk (16B units within a 64B row)
  const int swzc = lhi ^ ((l15 >> 1) & 3);
  const int aOff = l15 * 32 + swzc * 8;                      // A [64][32] at +0
  const int bOff = 2048 + (w * 64 + l15) * 32 + swzc * 8;    // B [256][32] at +2048 els

  // staging lane -> (row within 16-row chunk, chunk); LDS chunk (l&3) holds
  // global chunk (l&3) ^ ((row>>1)&3), row = l>>2
  const int sr = l >> 2;
  const int sc = (l & 3) ^ ((l >> 3) & 3);
  const unsigned short* PA = A  + (size_t)(m0 + w * 16 + sr) * K + sc * 8;  // A rows 16w..16w+15
  const unsigned short* PB = Bt + (size_t)(n0 + w * 64 + sr) * K + sc * 8;  // B rows 64w..64w+63

  // stage K-tile ts into slot: wave w loads A rows [16w,16w+16) (1 call) and
  // B rows [64w, 64w+64) (4 calls of 16 rows). 5 loads/wave.
#define STAGE64(ts, slot) do {                                                     \
    gload_lds16(PA + (size_t)(ts) * 32, &lds[(slot) * 10240 + w * 512]);           \
    gload_lds16(PB + (size_t)(ts) * 32,                                            \
                &lds[(slot) * 10240 + 2048 + w * 2048]);                           \
    gload_lds16(PB + (size_t)16 * K + (size_t)(ts) * 32,                           \
                &lds[(slot) * 10240 + 2048 + w * 2048 + 512]);                     \
    gload_lds16(PB + (size_t)32 * K + (size_t)(ts) * 32,                           \
                &lds[(slot) * 10240 + 2048 + w * 2048 + 1024]);                    \
    gload_lds16(PB + (size_t)48 * K + (size_t)(ts) * 32,                           \
                &lds[(slot) * 10240 + 2048 + w * 2048 + 1536]);                    \
  } while (0)

  f32x4 acc[4][4] = {};
  STAGE64(0, 0);
  STAGE64(1, 1);
  asm volatile("s_waitcnt vmcnt(5)" ::: "memory");   // tile 0 landed
  __builtin_amdgcn_sched_barrier(0);
  __builtin_amdgcn_s_barrier();

  const int NT = K >> 5;   // 32-col K-tiles
  int slotC = 0;           // t % 3
  for (int t = 0; t < NT; ++t) {
    const int base = slotC * 10240;
    const int ts = (t + 2 < NT) ? (t + 2) : (NT - 1);  // clamp keeps vmcnt symmetric
    int dslot = slotC + 2; if (dslot >= 3) dslot -= 3; // (t+2)%3
    STAGE64(ts, dslot);
    f16x8 af[4], bf[4];
#pragma unroll
    for (int q = 0; q < 4; ++q) af[q] = *reinterpret_cast<const f16x8*>(&lds[base + aOff + q * 512]);
#pragma unroll
    for (int q = 0; q < 4; ++q) bf[q] = *reinterpret_cast<const f16x8*>(&lds[base + bOff + q * 512]);
    asm volatile("s_waitcnt lgkmcnt(0)" ::: "memory");
    __builtin_amdgcn_sched_barrier(0);
    __builtin_amdgcn_s_setprio(1);
#pragma unroll
    for (int mi = 0; mi < 4; ++mi)
#pragma unroll
      for (int ni = 0; ni < 4; ++ni)
        acc[mi][ni] = __builtin_amdgcn_mfma_f32_16x16x32_f16(af[mi], bf[ni], acc[mi][ni], 0, 0, 0);
    __builtin_amdgcn_s_setprio(0);
    // drain stage(t+1)'s 5 loads, keep stage(t+2)'s 5 in flight
    asm volatile("s_waitcnt vmcnt(5)" ::: "memory");
    __builtin_amdgcn_sched_barrier(0);
    __builtin_amdgcn_s_barrier();
    ++slotC; if (slotC == 3) slotC = 0;
  }
#undef STAGE64
  asm volatile("s_waitcnt vmcnt(0)" ::: "memory");  // drain tail loads

  // epilogue; C/D frag layout: col = lane&15, row = (lane>>4)*4 + r
#pragma unroll
  for (int ni = 0; ni < 4; ++ni) {
    const int col = n0 + w * 64 + ni * 16 + l15;
    float bv = BIAS ? bias[col] : 0.0f;
#pragma unroll
    for (int mi = 0; mi < 4; ++mi) {
#pragma unroll
      for (int r = 0; r < 4; ++r) {
        const size_t row = (size_t)m0 + mi * 16 + lhi * 4 + r;
        float v = acc[mi][ni][r] + bv;
        if constexpr (F32OUT) __builtin_nontemporal_store(v, &Cf[row * (size_t)N + col]);
        else                  Ch[row * (size_t)N + col] = f2h_bits(v);
      }
    }
  }
}

// ---------------- causal flash attention (unchanged from R5)
__global__ __launch_bounds__(256) void attn_kernel(
    const unsigned short* __restrict__ qkv, unsigned short* __restrict__ out) {
  __shared__ unsigned short Vt[2][64 * 72];    // V^T tiles: [d][kv], padded
  __shared__ unsigned short Pl[4 * 16 * 72];   // per-wave P tile: [qrow][kv]
  const int bid = blockIdx.x;
  const int qt = bid & 31, bh = bid >> 5;
  const int b = bh >> 4, h = bh & 15;
  const int tid = threadIdx.x, w = tid >> 6, l = tid & 63;
  const int l15 = l & 15, lhi = l >> 4;
  const int q0 = qt * 64;
  const size_t RS = QKVN;  // row stride in elements
  const unsigned short* qbase = qkv + (size_t)b * TSEQ * RS + h * 64;
  const unsigned short* kbase = qbase + EDIM;
  const unsigned short* vbase = qbase + 2 * EDIM;

  f16x8 qa[2];
  {
    const int qrow = q0 + w * 16 + l15;
#pragma unroll
    for (int ks = 0; ks < 2; ++ks)
      qa[ks] = *reinterpret_cast<const f16x8*>(qbase + (size_t)qrow * RS + ks * 32 + lhi * 8);
  }
  const int vr_ = tid >> 3, vc8 = (tid & 7) * 8;
  {
#pragma unroll
    for (int p = 0; p < 2; ++p) {
      const int rr = vr_ + p * 32;
      u16x8v v = *reinterpret_cast<const u16x8v*>(vbase + (size_t)rr * RS + vc8);
#pragma unroll
      for (int j = 0; j < 8; ++j) Vt[0][(vc8 + j) * 72 + rr] = v[j];
    }
  }
  float m_run[4], l_run[4];
  f32x4 o[4] = {};
#pragma unroll
  for (int r = 0; r < 4; ++r) { m_run[r] = -__builtin_inff(); l_run[r] = 0.f; }
  const int myrow = q0 + w * 16 + lhi * 4;
  unsigned short* pl = &Pl[w * 16 * 72];
  __syncthreads();

  for (int kt = 0; kt <= qt; ++kt) {
    const int kv0 = kt * 64;
    const int tn = (kt + 1 <= qt) ? (kt + 1) : qt;
    u16x8v vpre[2];
#pragma unroll
    for (int p = 0; p < 2; ++p)
      vpre[p] = *reinterpret_cast<const u16x8v*>(
          vbase + (size_t)(tn * 64 + vr_ + p * 32) * RS + vc8);
    f32x4 s[4];
    __builtin_amdgcn_s_setprio(1);
#pragma unroll
    for (int ct = 0; ct < 4; ++ct) {
      f32x4 acc = {};
#pragma unroll
      for (int ks = 0; ks < 2; ++ks) {
        f16x8 kb = *reinterpret_cast<const f16x8*>(
            kbase + (size_t)(kv0 + ct * 16 + l15) * RS + ks * 32 + lhi * 8);
        acc = __builtin_amdgcn_mfma_f32_16x16x32_f16(qa[ks], kb, acc, 0, 0, 0);
      }
      s[ct] = acc;
    }
    __builtin_amdgcn_s_setprio(0);
    if (kt == qt) {
#pragma unroll
      for (int ct = 0; ct < 4; ++ct) {
        const int col = kv0 + ct * 16 + l15;
#pragma unroll
        for (int r = 0; r < 4; ++r) {
          float v = s[ct][r] * 0.125f;
          if (col > myrow + r) v = -__builtin_inff();
          s[ct][r] = v;
        }
      }
    } else {
#pragma unroll
      for (int ct = 0; ct < 4; ++ct)
#pragma unroll
        for (int r = 0; r < 4; ++r) s[ct][r] *= 0.125f;
    }
    float alpha[4];
#pragma unroll
    for (int r = 0; r < 4; ++r) {
      float mx = fmaxf(fmaxf(s[0][r], s[1][r]), fmaxf(s[2][r], s[3][r]));
      mx = fmaxf(mx, __shfl_xor(mx, 1)); mx = fmaxf(mx, __shfl_xor(mx, 2));
      mx = fmaxf(mx, __shfl_xor(mx, 4)); mx = fmaxf(mx, __shfl_xor(mx, 8));
      const float mn = fmaxf(m_run[r], mx);
      alpha[r] = __expf(m_run[r] - mn);
      m_run[r] = mn;
    }
    float rs[4] = {0.f, 0.f, 0.f, 0.f};
#pragma unroll
    for (int ct = 0; ct < 4; ++ct)
#pragma unroll
      for (int r = 0; r < 4; ++r) {
        const float p = __expf(s[ct][r] - m_run[r]);
        s[ct][r] = p;
        rs[r] += p;
      }
#pragma unroll
    for (int r = 0; r < 4; ++r) {
      float t = rs[r];
      t += __shfl_xor(t, 1); t += __shfl_xor(t, 2);
      t += __shfl_xor(t, 4); t += __shfl_xor(t, 8);
      l_run[r] = l_run[r] * alpha[r] + t;
    }
#pragma unroll
    for (int ct = 0; ct < 4; ++ct)
#pragma unroll
      for (int r = 0; r < 4; ++r) o[ct][r] *= alpha[r];
#pragma unroll
    for (int ct = 0; ct < 4; ++ct)
#pragma unroll
      for (int r = 0; r < 4; ++r)
        pl[(lhi * 4 + r) * 72 + ct * 16 + l15] = f2h_bits(s[ct][r]);
    const unsigned short* vt = Vt[kt & 1];
#pragma unroll
    for (int ks = 0; ks < 2; ++ks) {
      f16x8 pa = *reinterpret_cast<const f16x8*>(&pl[l15 * 72 + ks * 32 + lhi * 8]);
      __builtin_amdgcn_s_setprio(1);
#pragma unroll
      for (int ct = 0; ct < 4; ++ct) {
        f16x8 vb = *reinterpret_cast<const f16x8*>(&vt[(ct * 16 + l15) * 72 + ks * 32 + lhi * 8]);
        o[ct] = __builtin_amdgcn_mfma_f32_16x16x32_f16(pa, vb, o[ct], 0, 0, 0);
      }
      __builtin_amdgcn_s_setprio(0);
    }
    if (kt < qt) {
      unsigned short* vtn = Vt[(kt + 1) & 1];
#pragma unroll
      for (int p = 0; p < 2; ++p) {
        const int rr = vr_ + p * 32;
#pragma unroll
        for (int j = 0; j < 8; ++j) vtn[(vc8 + j) * 72 + rr] = vpre[p][j];
      }
    }
    __syncthreads();
  }
  unsigned short* obase = out + ((size_t)(b * TSEQ + q0 + w * 16)) * EDIM + h * 64;
#pragma unroll
  for (int r = 0; r < 4; ++r) {
    const float linv = 1.0f / l_run[r];
#pragma unroll
    for (int ct = 0; ct < 4; ++ct) {
      obase[(size_t)(lhi * 4 + r) * EDIM + ct * 16 + l15] = f2h_bits(o[ct][r] * linv);
    }
  }
}

extern "C" void kernel_launch(void* const* d_in, const int* in_sizes, int n_in,
                              void* d_out, int out_size, void* d_ws, size_t ws_size,
                              hipStream_t stream) {
  const int*   X    = (const int*)d_in[0];
  const float* tokE = (const float*)d_in[1];
  const float* posE = (const float*)d_in[2];
  const float* Wq   = (const float*)d_in[3];
  const float* Wk   = (const float*)d_in[4];
  const float* Wv   = (const float*)d_in[5];
  const float* lmW  = (const float*)d_in[6];
  const float* lmb  = (const float*)d_in[7];
  float* out = (float*)d_out;

  // workspace layout (f16 elements); total ~108.5 MB
  unsigned short* ws   = (unsigned short*)d_ws;
  unsigned short* x    = ws;                              // [4096,1024]
  unsigned short* att  = x    + (size_t)MROWS * EDIM;     // [4096,1024]
  unsigned short* wqkv = att  + (size_t)MROWS * EDIM;     // [3072,1024]
  unsigned short* qkv  = wqkv + (size_t)QKVN * EDIM;      // [4096,3072]
  unsigned short* lmWt = qkv  + (size_t)MROWS * QKVN;     // [32000,1024]

  embed_kernel<<<(MROWS * EDIM / 8) / 256, 256, 0, stream>>>(X, tokE, posE, x);
  trans_qkvw<<<3 * NH * (EDIM / 64), 256, 0, stream>>>(Wq, Wk, Wv, wqkv);
  trans_lmw<<<(VOC / 64) * (EDIM / 64), 256, 0, stream>>>(lmW, lmWt);
  // QKV proj: M=4096, N=3072, K=1024 -> 12*32 = 384 blocks
  gemm128<false, false><<<(QKVN / 256) * (MROWS / 128), 512, 0, stream>>>(
      x, wqkv, nullptr, qkv, nullptr, QKVN, EDIM);
  attn_kernel<<<NB * NH * (TSEQ / 64), 256, 0, stream>>>(qkv, att);
  // LM head: M=4096, N=32000, K=1024 -> 125 * 64 = 8000 blocks (BM=64)
  gemm64<true, true><<<(VOC / 256) * (MROWS / 64), 256, 0, stream>>>(
      att, lmWt, out, nullptr, lmb, VOC, EDIM);
}

// Round 7
// 524.344 us; speedup vs baseline: 1.2175x; 1.2175x over previous
//
#include <hip/hip_runtime.h>
#include <hip/hip_bf16.h>
#include <cstdint>

// Problem dims
#define TSEQ 2048
#define NB   2
#define NH   16
#define EDIM 1024
#define DDIM 64
#define VOC  32000
#define MROWS (NB*TSEQ)   // 4096
#define QKVN  (3*EDIM)    // 3072

typedef _Float16 f16x8 __attribute__((ext_vector_type(8)));
typedef float    f32x4 __attribute__((ext_vector_type(4)));
typedef unsigned short u16x4v __attribute__((ext_vector_type(4)));
typedef unsigned short u16x8v __attribute__((ext_vector_type(8)));

__device__ __forceinline__ unsigned short f2h_bits(float v) {
  return __builtin_bit_cast(unsigned short, (_Float16)v);
}

// async global->LDS, 16B per lane. LDS dest is wave-uniform base; lane i
// writes bytes [16*i, 16*i+16). Per-lane global source address is free.
__device__ __forceinline__ void gload_lds16(const void* g, void* l) {
  __builtin_amdgcn_global_load_lds((__attribute__((address_space(1))) void*)(g),
                                   (__attribute__((address_space(3))) void*)(l),
                                   16, 0, 0);
}

// ---------------- embedding: x[row,e] = tok_emb[X[row],e] + pos_emb[row%T,e] (f16 out)
__global__ __launch_bounds__(256) void embed_kernel(
    const int* __restrict__ X, const float* __restrict__ tokE,
    const float* __restrict__ posE, unsigned short* __restrict__ x) {
  int g = blockIdx.x * 256 + threadIdx.x;
  int row = g >> 7;            // 128 threads per row of 1024
  int e8  = (g & 127) * 8;
  int tk  = X[row];
  int tp  = row & (TSEQ - 1);
  const float4* ta = reinterpret_cast<const float4*>(&tokE[(size_t)tk * EDIM + e8]);
  const float4* pa = reinterpret_cast<const float4*>(&posE[(size_t)tp * EDIM + e8]);
  float4 a0 = ta[0], a1 = ta[1], p0 = pa[0], p1 = pa[1];
  u16x8v o;
  o[0] = f2h_bits(a0.x + p0.x); o[1] = f2h_bits(a0.y + p0.y);
  o[2] = f2h_bits(a0.z + p0.z); o[3] = f2h_bits(a0.w + p0.w);
  o[4] = f2h_bits(a1.x + p1.x); o[5] = f2h_bits(a1.y + p1.y);
  o[6] = f2h_bits(a1.z + p1.z); o[7] = f2h_bits(a1.w + p1.w);
  *reinterpret_cast<u16x8v*>(&x[(size_t)row * EDIM + e8]) = o;
}

// ---------------- W{q,k,v}[h,e,d] (f32) -> Wt[n=mat*1024+h*64+d][e] (f16)
__global__ __launch_bounds__(256) void trans_qkvw(
    const float* __restrict__ Wq, const float* __restrict__ Wk,
    const float* __restrict__ Wv, unsigned short* __restrict__ Wt) {
  __shared__ float ts[64][65];
  int bid = blockIdx.x;          // 3*16*16 = 768
  int mat = bid >> 8;
  int h   = (bid >> 4) & 15;
  int et  = bid & 15;
  const float* src = (mat == 0 ? Wq : (mat == 1 ? Wk : Wv)) + (size_t)h * EDIM * DDIM;
  int t = threadIdx.x;
  int rr = t >> 4, c4 = (t & 15) * 4;
#pragma unroll
  for (int p = 0; p < 4; ++p) {
    int r = p * 16 + rr;  // e within tile
    float4 v = *reinterpret_cast<const float4*>(&src[(size_t)(et * 64 + r) * DDIM + c4]);
    ts[r][c4 + 0] = v.x; ts[r][c4 + 1] = v.y; ts[r][c4 + 2] = v.z; ts[r][c4 + 3] = v.w;
  }
  __syncthreads();
#pragma unroll
  for (int p = 0; p < 4; ++p) {
    int dr = p * 16 + rr;  // d
    u16x4v o;
#pragma unroll
    for (int j = 0; j < 4; ++j) o[j] = f2h_bits(ts[c4 + j][dr]);
    *reinterpret_cast<u16x4v*>(&Wt[((size_t)(mat * EDIM + h * 64 + dr)) * EDIM + et * 64 + c4]) = o;
  }
}

// ---------------- lm_W[e,v] (f32) -> lm_Wt[v,e] (f16)
__global__ __launch_bounds__(256) void trans_lmw(
    const float* __restrict__ W, unsigned short* __restrict__ Wt) {
  __shared__ float ts[64][65];
  int bid = blockIdx.x;        // 500 * 16 = 8000
  int vt = bid / 16, et = bid % 16;
  int t = threadIdx.x;
  int rr = t >> 4, c4 = (t & 15) * 4;
#pragma unroll
  for (int p = 0; p < 4; ++p) {
    int r = p * 16 + rr;  // e within tile
    float4 v = *reinterpret_cast<const float4*>(&W[(size_t)(et * 64 + r) * VOC + vt * 64 + c4]);
    ts[r][c4 + 0] = v.x; ts[r][c4 + 1] = v.y; ts[r][c4 + 2] = v.z; ts[r][c4 + 3] = v.w;
  }
  __syncthreads();
#pragma unroll
  for (int p = 0; p < 4; ++p) {
    int vr = p * 16 + rr;  // v within tile
    u16x4v o;
#pragma unroll
    for (int j = 0; j < 4; ++j) o[j] = f2h_bits(ts[c4 + j][vr]);
    *reinterpret_cast<u16x4v*>(&Wt[(size_t)(vt * 64 + vr) * EDIM + et * 64 + c4]) = o;
  }
}

// ---------------- 128x256 GEMM (QKV proj): unchanged from R5 (proven)
template <bool F32OUT, bool BIAS>
__global__ __launch_bounds__(512, 4) void gemm128(
    const unsigned short* __restrict__ A, const unsigned short* __restrict__ Bt,
    float* __restrict__ Cf, unsigned short* __restrict__ Ch,
    const float* __restrict__ bias, int N, int K) {
  __shared__ __align__(16) unsigned short lds[3 * 12288];   // 72 KiB
  const int tid = threadIdx.x;
  const int w = tid >> 6, l = tid & 63;
  const int wr = w >> 2, wc = w & 3;      // 2 x 4 wave grid
  const int l15 = l & 15, lhi = l >> 4;
  const int orig = blockIdx.x;
  const int bx = orig >> 5;           // N-block
  const int by = orig & 31;           // M-block (fastest)
  const int m0 = by * 128, n0 = bx * 256;
  const int swzc = lhi ^ ((l15 >> 1) & 3);
  const int aOff = (wr * 64 + l15) * 32 + swzc * 8;
  const int bOff = 4096 + (wc * 64 + l15) * 32 + swzc * 8;
  const int sr = l >> 2;
  const int sc = (l & 3) ^ ((l >> 3) & 3);
  const unsigned short* PA = A  + (size_t)(m0 + w * 16 + sr) * K + sc * 8;
  const unsigned short* PB = Bt + (size_t)(n0 + w * 16 + sr) * K + sc * 8;
  const int dOff = w * 512;

#define STAGE32(ts, slot) do {                                                \
    gload_lds16(PA + (size_t)(ts) * 32, &lds[(slot) * 12288 + dOff]);         \
    gload_lds16(PB + (size_t)(ts) * 32, &lds[(slot) * 12288 + 4096 + dOff]);  \
    gload_lds16(PB + (size_t)128 * K + (size_t)(ts) * 32,                     \
                &lds[(slot) * 12288 + 8192 + dOff]);                          \
  } while (0)

  f32x4 acc[4][4] = {};
  STAGE32(0, 0);
  STAGE32(1, 1);
  asm volatile("s_waitcnt vmcnt(3)" ::: "memory");
  __builtin_amdgcn_sched_barrier(0);
  __builtin_amdgcn_s_barrier();

  const int NT = K >> 5;
  int slotC = 0;
  for (int t = 0; t < NT; ++t) {
    const int base = slotC * 12288;
    const int ts = (t + 2 < NT) ? (t + 2) : (NT - 1);
    int dslot = slotC + 2; if (dslot >= 3) dslot -= 3;
    STAGE32(ts, dslot);
    f16x8 af[4], bf[4];
#pragma unroll
    for (int q = 0; q < 4; ++q) af[q] = *reinterpret_cast<const f16x8*>(&lds[base + aOff + q * 512]);
#pragma unroll
    for (int q = 0; q < 4; ++q) bf[q] = *reinterpret_cast<const f16x8*>(&lds[base + bOff + q * 512]);
    asm volatile("s_waitcnt lgkmcnt(0)" ::: "memory");
    __builtin_amdgcn_sched_barrier(0);
    __builtin_amdgcn_s_setprio(1);
#pragma unroll
    for (int mi = 0; mi < 4; ++mi)
#pragma unroll
      for (int ni = 0; ni < 4; ++ni)
        acc[mi][ni] = __builtin_amdgcn_mfma_f32_16x16x32_f16(af[mi], bf[ni], acc[mi][ni], 0, 0, 0);
    __builtin_amdgcn_s_setprio(0);
    asm volatile("s_waitcnt vmcnt(3)" ::: "memory");
    __builtin_amdgcn_sched_barrier(0);
    __builtin_amdgcn_s_barrier();
    ++slotC; if (slotC == 3) slotC = 0;
  }
#undef STAGE32
  asm volatile("s_waitcnt vmcnt(0)" ::: "memory");

#pragma unroll
  for (int ni = 0; ni < 4; ++ni) {
    const int col = n0 + wc * 64 + ni * 16 + l15;
    float bv = BIAS ? bias[col] : 0.0f;
#pragma unroll
    for (int mi = 0; mi < 4; ++mi) {
#pragma unroll
      for (int r = 0; r < 4; ++r) {
        const size_t row = (size_t)m0 + wr * 64 + mi * 16 + lhi * 4 + r;
        float v = acc[mi][ni][r] + bv;
        if constexpr (F32OUT) __builtin_nontemporal_store(v, &Cf[row * (size_t)N + col]);
        else                  Ch[row * (size_t)N + col] = f2h_bits(v);
      }
    }
  }
}

// ---------------- 128x256 GEMM, WAVE TILE 128x64 (LM head).
// R6 post-mortem: all wave-64x64 structures plateau at 690-755 TF because
// 16 MFMA / 8 ds_read_b128 (32 FLOP per LDS byte) oversubscribes the LDS
// read pipe ~3x vs the matrix pipe. This kernel: 4 waves (1M x 4N), wave
// tile 128x64 -> 32 MFMA / 12 ds_read (42.7 FLOP/B), same proven 3-slot
// depth-2 counted pipeline (6 loads/wave/tile, vmcnt(6)), same chunk-XOR
// swizzle (measured 0 conflicts), M-fastest linear block order.
// LDS 3 x 24 KB = 72 KB -> 2 blocks/CU; acc=128 regs -> 2 waves/SIMD.
template <bool F32OUT, bool BIAS>
__global__ __launch_bounds__(256, 2) void gemm128w(
    const unsigned short* __restrict__ A, const unsigned short* __restrict__ Bt,
    float* __restrict__ Cf, unsigned short* __restrict__ Ch,
    const float* __restrict__ bias, int N, int K) {
  __shared__ __align__(16) unsigned short lds[3 * 12288];   // 72 KiB
  const int tid = threadIdx.x;
  const int w = tid >> 6, l = tid & 63;   // 4 waves; wave N-col = w
  const int l15 = l & 15, lhi = l >> 4;
  const int orig = blockIdx.x;
  const int bx = orig >> 5;           // N-block (125 or 12)
  const int by = orig & 31;           // M-block (fastest, 32)
  const int m0 = by * 128, n0 = bx * 256;

  // ds_read swizzled chunk (16B units within a 64B row)
  const int swzc = lhi ^ ((l15 >> 1) & 3);
  const int aOff = l15 * 32 + swzc * 8;                      // A [128][32] at +0
  const int bOff = 4096 + (w * 64 + l15) * 32 + swzc * 8;    // B [256][32] at +4096 els

  // staging lane -> (row, chunk); LDS chunk (l&3) holds global chunk
  // (l&3) ^ ((row>>1)&3), row = l>>2
  const int sr = l >> 2;
  const int sc = (l & 3) ^ ((l >> 3) & 3);
  const unsigned short* PA = A  + (size_t)(m0 + w * 16 + sr) * K + sc * 8;  // A rows 16w+sr
  const unsigned short* PB = Bt + (size_t)(n0 + w * 64 + sr) * K + sc * 8;  // B rows 64w+sr

  // stage K-tile ts into slot: wave w loads A rows {16w..16w+16, 64+16w..}
  // (2 calls) and B rows [64w, 64w+64) (4 calls). 6 loads/wave/tile.
#define STAGEW(ts, slot) do {                                                      \
    gload_lds16(PA + (size_t)(ts) * 32, &lds[(slot) * 12288 + w * 512]);           \
    gload_lds16(PA + (size_t)64 * K + (size_t)(ts) * 32,                           \
                &lds[(slot) * 12288 + 2048 + w * 512]);                            \
    gload_lds16(PB + (size_t)(ts) * 32,                                            \
                &lds[(slot) * 12288 + 4096 + w * 2048]);                           \
    gload_lds16(PB + (size_t)16 * K + (size_t)(ts) * 32,                           \
                &lds[(slot) * 12288 + 4096 + w * 2048 + 512]);                     \
    gload_lds16(PB + (size_t)32 * K + (size_t)(ts) * 32,                           \
                &lds[(slot) * 12288 + 4096 + w * 2048 + 1024]);                    \
    gload_lds16(PB + (size_t)48 * K + (size_t)(ts) * 32,                           \
                &lds[(slot) * 12288 + 4096 + w * 2048 + 1536]);                    \
  } while (0)

  f32x4 acc[8][4] = {};
  STAGEW(0, 0);
  STAGEW(1, 1);
  asm volatile("s_waitcnt vmcnt(6)" ::: "memory");   // tile 0 landed
  __builtin_amdgcn_sched_barrier(0);
  __builtin_amdgcn_s_barrier();

  const int NT = K >> 5;   // 32-col K-tiles
  int slotC = 0;           // t % 3
  for (int t = 0; t < NT; ++t) {
    const int base = slotC * 12288;
    const int ts = (t + 2 < NT) ? (t + 2) : (NT - 1);  // clamp keeps vmcnt symmetric
    int dslot = slotC + 2; if (dslot >= 3) dslot -= 3; // (t+2)%3
    STAGEW(ts, dslot);
    f16x8 af[8], bf[4];
#pragma unroll
    for (int q = 0; q < 8; ++q) af[q] = *reinterpret_cast<const f16x8*>(&lds[base + aOff + q * 512]);
#pragma unroll
    for (int q = 0; q < 4; ++q) bf[q] = *reinterpret_cast<const f16x8*>(&lds[base + bOff + q * 512]);
    asm volatile("s_waitcnt lgkmcnt(0)" ::: "memory");
    __builtin_amdgcn_sched_barrier(0);
    __builtin_amdgcn_s_setprio(1);
#pragma unroll
    for (int mi = 0; mi < 8; ++mi)
#pragma unroll
      for (int ni = 0; ni < 4; ++ni)
        acc[mi][ni] = __builtin_amdgcn_mfma_f32_16x16x32_f16(af[mi], bf[ni], acc[mi][ni], 0, 0, 0);
    __builtin_amdgcn_s_setprio(0);
    // drain stage(t+1)'s 6 loads, keep stage(t+2)'s 6 in flight
    asm volatile("s_waitcnt vmcnt(6)" ::: "memory");
    __builtin_amdgcn_sched_barrier(0);
    __builtin_amdgcn_s_barrier();
    ++slotC; if (slotC == 3) slotC = 0;
  }
#undef STAGEW
  asm volatile("s_waitcnt vmcnt(0)" ::: "memory");  // drain tail loads

  // epilogue; C/D frag layout: col = lane&15, row = (lane>>4)*4 + r
#pragma unroll
  for (int ni = 0; ni < 4; ++ni) {
    const int col = n0 + w * 64 + ni * 16 + l15;
    float bv = BIAS ? bias[col] : 0.0f;
#pragma unroll
    for (int mi = 0; mi < 8; ++mi) {
#pragma unroll
      for (int r = 0; r < 4; ++r) {
        const size_t row = (size_t)m0 + mi * 16 + lhi * 4 + r;
        float v = acc[mi][ni][r] + bv;
        if constexpr (F32OUT) __builtin_nontemporal_store(v, &Cf[row * (size_t)N + col]);
        else                  Ch[row * (size_t)N + col] = f2h_bits(v);
      }
    }
  }
}

// ---------------- causal flash attention (unchanged from R5)
__global__ __launch_bounds__(256) void attn_kernel(
    const unsigned short* __restrict__ qkv, unsigned short* __restrict__ out) {
  __shared__ unsigned short Vt[2][64 * 72];    // V^T tiles: [d][kv], padded
  __shared__ unsigned short Pl[4 * 16 * 72];   // per-wave P tile: [qrow][kv]
  const int bid = blockIdx.x;
  const int qt = bid & 31, bh = bid >> 5;
  const int b = bh >> 4, h = bh & 15;
  const int tid = threadIdx.x, w = tid >> 6, l = tid & 63;
  const int l15 = l & 15, lhi = l >> 4;
  const int q0 = qt * 64;
  const size_t RS = QKVN;  // row stride in elements
  const unsigned short* qbase = qkv + (size_t)b * TSEQ * RS + h * 64;
  const unsigned short* kbase = qbase + EDIM;
  const unsigned short* vbase = qbase + 2 * EDIM;

  f16x8 qa[2];
  {
    const int qrow = q0 + w * 16 + l15;
#pragma unroll
    for (int ks = 0; ks < 2; ++ks)
      qa[ks] = *reinterpret_cast<const f16x8*>(qbase + (size_t)qrow * RS + ks * 32 + lhi * 8);
  }
  const int vr_ = tid >> 3, vc8 = (tid & 7) * 8;
  {
#pragma unroll
    for (int p = 0; p < 2; ++p) {
      const int rr = vr_ + p * 32;
      u16x8v v = *reinterpret_cast<const u16x8v*>(vbase + (size_t)rr * RS + vc8);
#pragma unroll
      for (int j = 0; j < 8; ++j) Vt[0][(vc8 + j) * 72 + rr] = v[j];
    }
  }
  float m_run[4], l_run[4];
  f32x4 o[4] = {};
#pragma unroll
  for (int r = 0; r < 4; ++r) { m_run[r] = -__builtin_inff(); l_run[r] = 0.f; }
  const int myrow = q0 + w * 16 + lhi * 4;
  unsigned short* pl = &Pl[w * 16 * 72];
  __syncthreads();

  for (int kt = 0; kt <= qt; ++kt) {
    const int kv0 = kt * 64;
    const int tn = (kt + 1 <= qt) ? (kt + 1) : qt;
    u16x8v vpre[2];
#pragma unroll
    for (int p = 0; p < 2; ++p)
      vpre[p] = *reinterpret_cast<const u16x8v*>(
          vbase + (size_t)(tn * 64 + vr_ + p * 32) * RS + vc8);
    f32x4 s[4];
    __builtin_amdgcn_s_setprio(1);
#pragma unroll
    for (int ct = 0; ct < 4; ++ct) {
      f32x4 acc = {};
#pragma unroll
      for (int ks = 0; ks < 2; ++ks) {
        f16x8 kb = *reinterpret_cast<const f16x8*>(
            kbase + (size_t)(kv0 + ct * 16 + l15) * RS + ks * 32 + lhi * 8);
        acc = __builtin_amdgcn_mfma_f32_16x16x32_f16(qa[ks], kb, acc, 0, 0, 0);
      }
      s[ct] = acc;
    }
    __builtin_amdgcn_s_setprio(0);
    if (kt == qt) {
#pragma unroll
      for (int ct = 0; ct < 4; ++ct) {
        const int col = kv0 + ct * 16 + l15;
#pragma unroll
        for (int r = 0; r < 4; ++r) {
          float v = s[ct][r] * 0.125f;
          if (col > myrow + r) v = -__builtin_inff();
          s[ct][r] = v;
        }
      }
    } else {
#pragma unroll
      for (int ct = 0; ct < 4; ++ct)
#pragma unroll
        for (int r = 0; r < 4; ++r) s[ct][r] *= 0.125f;
    }
    float alpha[4];
#pragma unroll
    for (int r = 0; r < 4; ++r) {
      float mx = fmaxf(fmaxf(s[0][r], s[1][r]), fmaxf(s[2][r], s[3][r]));
      mx = fmaxf(mx, __shfl_xor(mx, 1)); mx = fmaxf(mx, __shfl_xor(mx, 2));
      mx = fmaxf(mx, __shfl_xor(mx, 4)); mx = fmaxf(mx, __shfl_xor(mx, 8));
      const float mn = fmaxf(m_run[r], mx);
      alpha[r] = __expf(m_run[r] - mn);
      m_run[r] = mn;
    }
    float rs[4] = {0.f, 0.f, 0.f, 0.f};
#pragma unroll
    for (int ct = 0; ct < 4; ++ct)
#pragma unroll
      for (int r = 0; r < 4; ++r) {
        const float p = __expf(s[ct][r] - m_run[r]);
        s[ct][r] = p;
        rs[r] += p;
      }
#pragma unroll
    for (int r = 0; r < 4; ++r) {
      float t = rs[r];
      t += __shfl_xor(t, 1); t += __shfl_xor(t, 2);
      t += __shfl_xor(t, 4); t += __shfl_xor(t, 8);
      l_run[r] = l_run[r] * alpha[r] + t;
    }
#pragma unroll
    for (int ct = 0; ct < 4; ++ct)
#pragma unroll
      for (int r = 0; r < 4; ++r) o[ct][r] *= alpha[r];
#pragma unroll
    for (int ct = 0; ct < 4; ++ct)
#pragma unroll
      for (int r = 0; r < 4; ++r)
        pl[(lhi * 4 + r) * 72 + ct * 16 + l15] = f2h_bits(s[ct][r]);
    const unsigned short* vt = Vt[kt & 1];
#pragma unroll
    for (int ks = 0; ks < 2; ++ks) {
      f16x8 pa = *reinterpret_cast<const f16x8*>(&pl[l15 * 72 + ks * 32 + lhi * 8]);
      __builtin_amdgcn_s_setprio(1);
#pragma unroll
      for (int ct = 0; ct < 4; ++ct) {
        f16x8 vb = *reinterpret_cast<const f16x8*>(&vt[(ct * 16 + l15) * 72 + ks * 32 + lhi * 8]);
        o[ct] = __builtin_amdgcn_mfma_f32_16x16x32_f16(pa, vb, o[ct], 0, 0, 0);
      }
      __builtin_amdgcn_s_setprio(0);
    }
    if (kt < qt) {
      unsigned short* vtn = Vt[(kt + 1) & 1];
#pragma unroll
      for (int p = 0; p < 2; ++p) {
        const int rr = vr_ + p * 32;
#pragma unroll
        for (int j = 0; j < 8; ++j) vtn[(vc8 + j) * 72 + rr] = vpre[p][j];
      }
    }
    __syncthreads();
  }
  unsigned short* obase = out + ((size_t)(b * TSEQ + q0 + w * 16)) * EDIM + h * 64;
#pragma unroll
  for (int r = 0; r < 4; ++r) {
    const float linv = 1.0f / l_run[r];
#pragma unroll
    for (int ct = 0; ct < 4; ++ct) {
      obase[(size_t)(lhi * 4 + r) * EDIM + ct * 16 + l15] = f2h_bits(o[ct][r] * linv);
    }
  }
}

extern "C" void kernel_launch(void* const* d_in, const int* in_sizes, int n_in,
                              void* d_out, int out_size, void* d_ws, size_t ws_size,
                              hipStream_t stream) {
  const int*   X    = (const int*)d_in[0];
  const float* tokE = (const float*)d_in[1];
  const float* posE = (const float*)d_in[2];
  const float* Wq   = (const float*)d_in[3];
  const float* Wk   = (const float*)d_in[4];
  const float* Wv   = (const float*)d_in[5];
  const float* lmW  = (const float*)d_in[6];
  const float* lmb  = (const float*)d_in[7];
  float* out = (float*)d_out;

  // workspace layout (f16 elements); total ~108.5 MB
  unsigned short* ws   = (unsigned short*)d_ws;
  unsigned short* x    = ws;                              // [4096,1024]
  unsigned short* att  = x    + (size_t)MROWS * EDIM;     // [4096,1024]
  unsigned short* wqkv = att  + (size_t)MROWS * EDIM;     // [3072,1024]
  unsigned short* qkv  = wqkv + (size_t)QKVN * EDIM;      // [4096,3072]
  unsigned short* lmWt = qkv  + (size_t)MROWS * QKVN;     // [32000,1024]

  embed_kernel<<<(MROWS * EDIM / 8) / 256, 256, 0, stream>>>(X, tokE, posE, x);
  trans_qkvw<<<3 * NH * (EDIM / 64), 256, 0, stream>>>(Wq, Wk, Wv, wqkv);
  trans_lmw<<<(VOC / 64) * (EDIM / 64), 256, 0, stream>>>(lmW, lmWt);
  // QKV proj: M=4096, N=3072, K=1024 -> 12*32 = 384 blocks (proven gemm128)
  gemm128<false, false><<<(QKVN / 256) * (MROWS / 128), 512, 0, stream>>>(
      x, wqkv, nullptr, qkv, nullptr, QKVN, EDIM);
  attn_kernel<<<NB * NH * (TSEQ / 64), 256, 0, stream>>>(qkv, att);
  // LM head: M=4096, N=32000, K=1024 -> 125*32 = 4000 blocks, wave tile 128x64
  gemm128w<true, true><<<(VOC / 256) * (MROWS / 128), 256, 0, stream>>>(
      att, lmWt, out, nullptr, lmb, VOC, EDIM);
}

// Round 8
// 523.138 us; speedup vs baseline: 1.2203x; 1.0023x over previous
//
#include <hip/hip_runtime.h>
#include <hip/hip_bf16.h>
#include <cstdint>

// Problem dims
#define TSEQ 2048
#define NB   2
#define NH   16
#define EDIM 1024
#define DDIM 64
#define VOC  32000
#define MROWS (NB*TSEQ)   // 4096
#define QKVN  (3*EDIM)    // 3072

typedef _Float16 f16x8 __attribute__((ext_vector_type(8)));
typedef float    f32x4 __attribute__((ext_vector_type(4)));
typedef unsigned short u16x4v __attribute__((ext_vector_type(4)));
typedef unsigned short u16x8v __attribute__((ext_vector_type(8)));

__device__ __forceinline__ unsigned short f2h_bits(float v) {
  return __builtin_bit_cast(unsigned short, (_Float16)v);
}

// async global->LDS, 16B per lane. LDS dest is wave-uniform base; lane i
// writes bytes [16*i, 16*i+16). Per-lane global source address is free.
__device__ __forceinline__ void gload_lds16(const void* g, void* l) {
  __builtin_amdgcn_global_load_lds((__attribute__((address_space(1))) void*)(g),
                                   (__attribute__((address_space(3))) void*)(l),
                                   16, 0, 0);
}

// ---------------- embedding: x[row,e] = tok_emb[X[row],e] + pos_emb[row%T,e] (f16 out)
__global__ __launch_bounds__(256) void embed_kernel(
    const int* __restrict__ X, const float* __restrict__ tokE,
    const float* __restrict__ posE, unsigned short* __restrict__ x) {
  int g = blockIdx.x * 256 + threadIdx.x;
  int row = g >> 7;            // 128 threads per row of 1024
  int e8  = (g & 127) * 8;
  int tk  = X[row];
  int tp  = row & (TSEQ - 1);
  const float4* ta = reinterpret_cast<const float4*>(&tokE[(size_t)tk * EDIM + e8]);
  const float4* pa = reinterpret_cast<const float4*>(&posE[(size_t)tp * EDIM + e8]);
  float4 a0 = ta[0], a1 = ta[1], p0 = pa[0], p1 = pa[1];
  u16x8v o;
  o[0] = f2h_bits(a0.x + p0.x); o[1] = f2h_bits(a0.y + p0.y);
  o[2] = f2h_bits(a0.z + p0.z); o[3] = f2h_bits(a0.w + p0.w);
  o[4] = f2h_bits(a1.x + p1.x); o[5] = f2h_bits(a1.y + p1.y);
  o[6] = f2h_bits(a1.z + p1.z); o[7] = f2h_bits(a1.w + p1.w);
  *reinterpret_cast<u16x8v*>(&x[(size_t)row * EDIM + e8]) = o;
}

// ---------------- W{q,k,v}[h,e,d] (f32) -> Wt[n=mat*1024+h*64+d][e] (f16)
__global__ __launch_bounds__(256) void trans_qkvw(
    const float* __restrict__ Wq, const float* __restrict__ Wk,
    const float* __restrict__ Wv, unsigned short* __restrict__ Wt) {
  __shared__ float ts[64][65];
  int bid = blockIdx.x;          // 3*16*16 = 768
  int mat = bid >> 8;
  int h   = (bid >> 4) & 15;
  int et  = bid & 15;
  const float* src = (mat == 0 ? Wq : (mat == 1 ? Wk : Wv)) + (size_t)h * EDIM * DDIM;
  int t = threadIdx.x;
  int rr = t >> 4, c4 = (t & 15) * 4;
#pragma unroll
  for (int p = 0; p < 4; ++p) {
    int r = p * 16 + rr;  // e within tile
    float4 v = *reinterpret_cast<const float4*>(&src[(size_t)(et * 64 + r) * DDIM + c4]);
    ts[r][c4 + 0] = v.x; ts[r][c4 + 1] = v.y; ts[r][c4 + 2] = v.z; ts[r][c4 + 3] = v.w;
  }
  __syncthreads();
#pragma unroll
  for (int p = 0; p < 4; ++p) {
    int dr = p * 16 + rr;  // d
    u16x4v o;
#pragma unroll
    for (int j = 0; j < 4; ++j) o[j] = f2h_bits(ts[c4 + j][dr]);
    *reinterpret_cast<u16x4v*>(&Wt[((size_t)(mat * EDIM + h * 64 + dr)) * EDIM + et * 64 + c4]) = o;
  }
}

// ---------------- lm_W[e,v] (f32) -> lm_Wt[v,e] (f16)
__global__ __launch_bounds__(256) void trans_lmw(
    const float* __restrict__ W, unsigned short* __restrict__ Wt) {
  __shared__ float ts[64][65];
  int bid = blockIdx.x;        // 500 * 16 = 8000
  int vt = bid / 16, et = bid % 16;
  int t = threadIdx.x;
  int rr = t >> 4, c4 = (t & 15) * 4;
#pragma unroll
  for (int p = 0; p < 4; ++p) {
    int r = p * 16 + rr;  // e within tile
    float4 v = *reinterpret_cast<const float4*>(&W[(size_t)(et * 64 + r) * VOC + vt * 64 + c4]);
    ts[r][c4 + 0] = v.x; ts[r][c4 + 1] = v.y; ts[r][c4 + 2] = v.z; ts[r][c4 + 3] = v.w;
  }
  __syncthreads();
#pragma unroll
  for (int p = 0; p < 4; ++p) {
    int vr = p * 16 + rr;  // v within tile
    u16x4v o;
#pragma unroll
    for (int j = 0; j < 4; ++j) o[j] = f2h_bits(ts[c4 + j][vr]);
    *reinterpret_cast<u16x4v*>(&Wt[(size_t)(vt * 64 + vr) * EDIM + et * 64 + c4]) = o;
  }
}

// ---------------- 128x256 GEMM (QKV proj), wave tile 64x64, 8 waves.
// R8: removed the lgkmcnt(0)+sched_barrier fence between fragment ds_reads
// and MFMAs -- those loads are compiler-visible, so hipcc emits fine-grained
// counted lgkmcnt and interleaves ds_read with MFMA (m97 evidence). The
// staging vmcnt(N)+barrier pair stays (global_load_lds is NOT compiler-
// trackable). Body hand-pipelined: bf[4]+af[0] up front, af[mi+1] issued
// before the 4 MFMAs on af[mi].
template <bool F32OUT, bool BIAS>
__global__ __launch_bounds__(512, 4) void gemm128(
    const unsigned short* __restrict__ A, const unsigned short* __restrict__ Bt,
    float* __restrict__ Cf, unsigned short* __restrict__ Ch,
    const float* __restrict__ bias, int N, int K) {
  __shared__ __align__(16) unsigned short lds[3 * 12288];   // 72 KiB
  const int tid = threadIdx.x;
  const int w = tid >> 6, l = tid & 63;
  const int wr = w >> 2, wc = w & 3;      // 2 x 4 wave grid
  const int l15 = l & 15, lhi = l >> 4;
  const int orig = blockIdx.x;
  const int bx = orig >> 5;           // N-block
  const int by = orig & 31;           // M-block (fastest)
  const int m0 = by * 128, n0 = bx * 256;
  const int swzc = lhi ^ ((l15 >> 1) & 3);
  const int aOff = (wr * 64 + l15) * 32 + swzc * 8;
  const int bOff = 4096 + (wc * 64 + l15) * 32 + swzc * 8;
  const int sr = l >> 2;
  const int sc = (l & 3) ^ ((l >> 3) & 3);
  const unsigned short* PA = A  + (size_t)(m0 + w * 16 + sr) * K + sc * 8;
  const unsigned short* PB = Bt + (size_t)(n0 + w * 16 + sr) * K + sc * 8;
  const int dOff = w * 512;

#define STAGE32(ts, slot) do {                                                \
    gload_lds16(PA + (size_t)(ts) * 32, &lds[(slot) * 12288 + dOff]);         \
    gload_lds16(PB + (size_t)(ts) * 32, &lds[(slot) * 12288 + 4096 + dOff]);  \
    gload_lds16(PB + (size_t)128 * K + (size_t)(ts) * 32,                     \
                &lds[(slot) * 12288 + 8192 + dOff]);                          \
  } while (0)

  f32x4 acc[4][4] = {};
  STAGE32(0, 0);
  STAGE32(1, 1);
  asm volatile("s_waitcnt vmcnt(3)" ::: "memory");
  __builtin_amdgcn_sched_barrier(0);
  __builtin_amdgcn_s_barrier();

  const int NT = K >> 5;
  int slotC = 0;
  for (int t = 0; t < NT; ++t) {
    const int base = slotC * 12288;
    const int ts = (t + 2 < NT) ? (t + 2) : (NT - 1);
    int dslot = slotC + 2; if (dslot >= 3) dslot -= 3;
    STAGE32(ts, dslot);
    f16x8 bf[4];
#pragma unroll
    for (int q = 0; q < 4; ++q) bf[q] = *reinterpret_cast<const f16x8*>(&lds[base + bOff + q * 512]);
    f16x8 afq = *reinterpret_cast<const f16x8*>(&lds[base + aOff]);
    __builtin_amdgcn_s_setprio(1);
#pragma unroll
    for (int mi = 0; mi < 4; ++mi) {
      f16x8 afn = *reinterpret_cast<const f16x8*>(&lds[base + aOff + (((mi + 1) & 3)) * 512]);
#pragma unroll
      for (int ni = 0; ni < 4; ++ni)
        acc[mi][ni] = __builtin_amdgcn_mfma_f32_16x16x32_f16(afq, bf[ni], acc[mi][ni], 0, 0, 0);
      afq = afn;
    }
    __builtin_amdgcn_s_setprio(0);
    asm volatile("s_waitcnt vmcnt(3)" ::: "memory");
    __builtin_amdgcn_sched_barrier(0);
    __builtin_amdgcn_s_barrier();
    ++slotC; if (slotC == 3) slotC = 0;
  }
#undef STAGE32
  asm volatile("s_waitcnt vmcnt(0)" ::: "memory");

#pragma unroll
  for (int ni = 0; ni < 4; ++ni) {
    const int col = n0 + wc * 64 + ni * 16 + l15;
    float bv = BIAS ? bias[col] : 0.0f;
#pragma unroll
    for (int mi = 0; mi < 4; ++mi) {
#pragma unroll
      for (int r = 0; r < 4; ++r) {
        const size_t row = (size_t)m0 + wr * 64 + mi * 16 + lhi * 4 + r;
        float v = acc[mi][ni][r] + bv;
        if constexpr (F32OUT) __builtin_nontemporal_store(v, &Cf[row * (size_t)N + col]);
        else                  Ch[row * (size_t)N + col] = f2h_bits(v);
      }
    }
  }
}

// ---------------- 128x256 GEMM, WAVE TILE 128x64 (LM head).
// R8: same de-serialization as gemm128 -- no lgkmcnt(0) fence before the
// MFMA cluster; hand-pipelined af stream (issue af[mi+1] load, then 4 MFMAs
// on af[mi]) so ds_read latency hides under MFMA within the wave. Staging
// vmcnt(6)+barrier pipeline, chunk-XOR swizzle (0 conflicts), M-fastest
// linear block order all unchanged (proven R7).
template <bool F32OUT, bool BIAS>
__global__ __launch_bounds__(256, 2) void gemm128w(
    const unsigned short* __restrict__ A, const unsigned short* __restrict__ Bt,
    float* __restrict__ Cf, unsigned short* __restrict__ Ch,
    const float* __restrict__ bias, int N, int K) {
  __shared__ __align__(16) unsigned short lds[3 * 12288];   // 72 KiB
  const int tid = threadIdx.x;
  const int w = tid >> 6, l = tid & 63;   // 4 waves; wave N-col = w
  const int l15 = l & 15, lhi = l >> 4;
  const int orig = blockIdx.x;
  const int bx = orig >> 5;           // N-block (125 or 12)
  const int by = orig & 31;           // M-block (fastest, 32)
  const int m0 = by * 128, n0 = bx * 256;

  // ds_read swizzled chunk (16B units within a 64B row)
  const int swzc = lhi ^ ((l15 >> 1) & 3);
  const int aOff = l15 * 32 + swzc * 8;                      // A [128][32] at +0
  const int bOff = 4096 + (w * 64 + l15) * 32 + swzc * 8;    // B [256][32] at +4096 els

  // staging lane -> (row, chunk); LDS chunk (l&3) holds global chunk
  // (l&3) ^ ((row>>1)&3), row = l>>2
  const int sr = l >> 2;
  const int sc = (l & 3) ^ ((l >> 3) & 3);
  const unsigned short* PA = A  + (size_t)(m0 + w * 16 + sr) * K + sc * 8;  // A rows 16w+sr
  const unsigned short* PB = Bt + (size_t)(n0 + w * 64 + sr) * K + sc * 8;  // B rows 64w+sr

  // stage K-tile ts into slot: wave w loads A rows {16w..16w+16, 64+16w..}
  // (2 calls) and B rows [64w, 64w+64) (4 calls). 6 loads/wave/tile.
#define STAGEW(ts, slot) do {                                                      \
    gload_lds16(PA + (size_t)(ts) * 32, &lds[(slot) * 12288 + w * 512]);           \
    gload_lds16(PA + (size_t)64 * K + (size_t)(ts) * 32,                           \
                &lds[(slot) * 12288 + 2048 + w * 512]);                            \
    gload_lds16(PB + (size_t)(ts) * 32,                                            \
                &lds[(slot) * 12288 + 4096 + w * 2048]);                           \
    gload_lds16(PB + (size_t)16 * K + (size_t)(ts) * 32,                           \
                &lds[(slot) * 12288 + 4096 + w * 2048 + 512]);                     \
    gload_lds16(PB + (size_t)32 * K + (size_t)(ts) * 32,                           \
                &lds[(slot) * 12288 + 4096 + w * 2048 + 1024]);                    \
    gload_lds16(PB + (size_t)48 * K + (size_t)(ts) * 32,                           \
                &lds[(slot) * 12288 + 4096 + w * 2048 + 1536]);                    \
  } while (0)

  f32x4 acc[8][4] = {};
  STAGEW(0, 0);
  STAGEW(1, 1);
  asm volatile("s_waitcnt vmcnt(6)" ::: "memory");   // tile 0 landed
  __builtin_amdgcn_sched_barrier(0);
  __builtin_amdgcn_s_barrier();

  const int NT = K >> 5;   // 32-col K-tiles
  int slotC = 0;           // t % 3
  for (int t = 0; t < NT; ++t) {
    const int base = slotC * 12288;
    const int ts = (t + 2 < NT) ? (t + 2) : (NT - 1);  // clamp keeps vmcnt symmetric
    int dslot = slotC + 2; if (dslot >= 3) dslot -= 3; // (t+2)%3
    STAGEW(ts, dslot);
    f16x8 bf[4];
#pragma unroll
    for (int q = 0; q < 4; ++q) bf[q] = *reinterpret_cast<const f16x8*>(&lds[base + bOff + q * 512]);
    f16x8 afq = *reinterpret_cast<const f16x8*>(&lds[base + aOff]);
    __builtin_amdgcn_s_setprio(1);
#pragma unroll
    for (int mi = 0; mi < 8; ++mi) {
      f16x8 afn = *reinterpret_cast<const f16x8*>(&lds[base + aOff + (((mi + 1) & 7)) * 512]);
#pragma unroll
      for (int ni = 0; ni < 4; ++ni)
        acc[mi][ni] = __builtin_amdgcn_mfma_f32_16x16x32_f16(afq, bf[ni], acc[mi][ni], 0, 0, 0);
      afq = afn;
    }
    __builtin_amdgcn_s_setprio(0);
    // drain stage(t+1)'s 6 loads, keep stage(t+2)'s 6 in flight
    asm volatile("s_waitcnt vmcnt(6)" ::: "memory");
    __builtin_amdgcn_sched_barrier(0);
    __builtin_amdgcn_s_barrier();
    ++slotC; if (slotC == 3) slotC = 0;
  }
#undef STAGEW
  asm volatile("s_waitcnt vmcnt(0)" ::: "memory");  // drain tail loads

  // epilogue; C/D frag layout: col = lane&15, row = (lane>>4)*4 + r
#pragma unroll
  for (int ni = 0; ni < 4; ++ni) {
    const int col = n0 + w * 64 + ni * 16 + l15;
    float bv = BIAS ? bias[col] : 0.0f;
#pragma unroll
    for (int mi = 0; mi < 8; ++mi) {
#pragma unroll
      for (int r = 0; r < 4; ++r) {
        const size_t row = (size_t)m0 + mi * 16 + lhi * 4 + r;
        float v = acc[mi][ni][r] + bv;
        if constexpr (F32OUT) __builtin_nontemporal_store(v, &Cf[row * (size_t)N + col]);
        else                  Ch[row * (size_t)N + col] = f2h_bits(v);
      }
    }
  }
}

// ---------------- causal flash attention (unchanged from R5)
__global__ __launch_bounds__(256) void attn_kernel(
    const unsigned short* __restrict__ qkv, unsigned short* __restrict__ out) {
  __shared__ unsigned short Vt[2][64 * 72];    // V^T tiles: [d][kv], padded
  __shared__ unsigned short Pl[4 * 16 * 72];   // per-wave P tile: [qrow][kv]
  const int bid = blockIdx.x;
  const int qt = bid & 31, bh = bid >> 5;
  const int b = bh >> 4, h = bh & 15;
  const int tid = threadIdx.x, w = tid >> 6, l = tid & 63;
  const int l15 = l & 15, lhi = l >> 4;
  const int q0 = qt * 64;
  const size_t RS = QKVN;  // row stride in elements
  const unsigned short* qbase = qkv + (size_t)b * TSEQ * RS + h * 64;
  const unsigned short* kbase = qbase + EDIM;
  const unsigned short* vbase = qbase + 2 * EDIM;

  f16x8 qa[2];
  {
    const int qrow = q0 + w * 16 + l15;
#pragma unroll
    for (int ks = 0; ks < 2; ++ks)
      qa[ks] = *reinterpret_cast<const f16x8*>(qbase + (size_t)qrow * RS + ks * 32 + lhi * 8);
  }
  const int vr_ = tid >> 3, vc8 = (tid & 7) * 8;
  {
#pragma unroll
    for (int p = 0; p < 2; ++p) {
      const int rr = vr_ + p * 32;
      u16x8v v = *reinterpret_cast<const u16x8v*>(vbase + (size_t)rr * RS + vc8);
#pragma unroll
      for (int j = 0; j < 8; ++j) Vt[0][(vc8 + j) * 72 + rr] = v[j];
    }
  }
  float m_run[4], l_run[4];
  f32x4 o[4] = {};
#pragma unroll
  for (int r = 0; r < 4; ++r) { m_run[r] = -__builtin_inff(); l_run[r] = 0.f; }
  const int myrow = q0 + w * 16 + lhi * 4;
  unsigned short* pl = &Pl[w * 16 * 72];
  __syncthreads();

  for (int kt = 0; kt <= qt; ++kt) {
    const int kv0 = kt * 64;
    const int tn = (kt + 1 <= qt) ? (kt + 1) : qt;
    u16x8v vpre[2];
#pragma unroll
    for (int p = 0; p < 2; ++p)
      vpre[p] = *reinterpret_cast<const u16x8v*>(
          vbase + (size_t)(tn * 64 + vr_ + p * 32) * RS + vc8);
    f32x4 s[4];
    __builtin_amdgcn_s_setprio(1);
#pragma unroll
    for (int ct = 0; ct < 4; ++ct) {
      f32x4 acc = {};
#pragma unroll
      for (int ks = 0; ks < 2; ++ks) {
        f16x8 kb = *reinterpret_cast<const f16x8*>(
            kbase + (size_t)(kv0 + ct * 16 + l15) * RS + ks * 32 + lhi * 8);
        acc = __builtin_amdgcn_mfma_f32_16x16x32_f16(qa[ks], kb, acc, 0, 0, 0);
      }
      s[ct] = acc;
    }
    __builtin_amdgcn_s_setprio(0);
    if (kt == qt) {
#pragma unroll
      for (int ct = 0; ct < 4; ++ct) {
        const int col = kv0 + ct * 16 + l15;
#pragma unroll
        for (int r = 0; r < 4; ++r) {
          float v = s[ct][r] * 0.125f;
          if (col > myrow + r) v = -__builtin_inff();
          s[ct][r] = v;
        }
      }
    } else {
#pragma unroll
      for (int ct = 0; ct < 4; ++ct)
#pragma unroll
        for (int r = 0; r < 4; ++r) s[ct][r] *= 0.125f;
    }
    float alpha[4];
#pragma unroll
    for (int r = 0; r < 4; ++r) {
      float mx = fmaxf(fmaxf(s[0][r], s[1][r]), fmaxf(s[2][r], s[3][r]));
      mx = fmaxf(mx, __shfl_xor(mx, 1)); mx = fmaxf(mx, __shfl_xor(mx, 2));
      mx = fmaxf(mx, __shfl_xor(mx, 4)); mx = fmaxf(mx, __shfl_xor(mx, 8));
      const float mn = fmaxf(m_run[r], mx);
      alpha[r] = __expf(m_run[r] - mn);
      m_run[r] = mn;
    }
    float rs[4] = {0.f, 0.f, 0.f, 0.f};
#pragma unroll
    for (int ct = 0; ct < 4; ++ct)
#pragma unroll
      for (int r = 0; r < 4; ++r) {
        const float p = __expf(s[ct][r] - m_run[r]);
        s[ct][r] = p;
        rs[r] += p;
      }
#pragma unroll
    for (int r = 0; r < 4; ++r) {
      float t = rs[r];
      t += __shfl_xor(t, 1); t += __shfl_xor(t, 2);
      t += __shfl_xor(t, 4); t += __shfl_xor(t, 8);
      l_run[r] = l_run[r] * alpha[r] + t;
    }
#pragma unroll
    for (int ct = 0; ct < 4; ++ct)
#pragma unroll
      for (int r = 0; r < 4; ++r) o[ct][r] *= alpha[r];
#pragma unroll
    for (int ct = 0; ct < 4; ++ct)
#pragma unroll
      for (int r = 0; r < 4; ++r)
        pl[(lhi * 4 + r) * 72 + ct * 16 + l15] = f2h_bits(s[ct][r]);
    const unsigned short* vt = Vt[kt & 1];
#pragma unroll
    for (int ks = 0; ks < 2; ++ks) {
      f16x8 pa = *reinterpret_cast<const f16x8*>(&pl[l15 * 72 + ks * 32 + lhi * 8]);
      __builtin_amdgcn_s_setprio(1);
#pragma unroll
      for (int ct = 0; ct < 4; ++ct) {
        f16x8 vb = *reinterpret_cast<const f16x8*>(&vt[(ct * 16 + l15) * 72 + ks * 32 + lhi * 8]);
        o[ct] = __builtin_amdgcn_mfma_f32_16x16x32_f16(pa, vb, o[ct], 0, 0, 0);
      }
      __builtin_amdgcn_s_setprio(0);
    }
    if (kt < qt) {
      unsigned short* vtn = Vt[(kt + 1) & 1];
#pragma unroll
      for (int p = 0; p < 2; ++p) {
        const int rr = vr_ + p * 32;
#pragma unroll
        for (int j = 0; j < 8; ++j) vtn[(vc8 + j) * 72 + rr] = vpre[p][j];
      }
    }
    __syncthreads();
  }
  unsigned short* obase = out + ((size_t)(b * TSEQ + q0 + w * 16)) * EDIM + h * 64;
#pragma unroll
  for (int r = 0; r < 4; ++r) {
    const float linv = 1.0f / l_run[r];
#pragma unroll
    for (int ct = 0; ct < 4; ++ct) {
      obase[(size_t)(lhi * 4 + r) * EDIM + ct * 16 + l15] = f2h_bits(o[ct][r] * linv);
    }
  }
}

extern "C" void kernel_launch(void* const* d_in, const int* in_sizes, int n_in,
                              void* d_out, int out_size, void* d_ws, size_t ws_size,
                              hipStream_t stream) {
  const int*   X    = (const int*)d_in[0];
  const float* tokE = (const float*)d_in[1];
  const float* posE = (const float*)d_in[2];
  const float* Wq   = (const float*)d_in[3];
  const float* Wk   = (const float*)d_in[4];
  const float* Wv   = (const float*)d_in[5];
  const float* lmW  = (const float*)d_in[6];
  const float* lmb  = (const float*)d_in[7];
  float* out = (float*)d_out;

  // workspace layout (f16 elements); total ~108.5 MB
  unsigned short* ws   = (unsigned short*)d_ws;
  unsigned short* x    = ws;                              // [4096,1024]
  unsigned short* att  = x    + (size_t)MROWS * EDIM;     // [4096,1024]
  unsigned short* wqkv = att  + (size_t)MROWS * EDIM;     // [3072,1024]
  unsigned short* qkv  = wqkv + (size_t)QKVN * EDIM;      // [4096,3072]
  unsigned short* lmWt = qkv  + (size_t)MROWS * QKVN;     // [32000,1024]

  embed_kernel<<<(MROWS * EDIM / 8) / 256, 256, 0, stream>>>(X, tokE, posE, x);
  trans_qkvw<<<3 * NH * (EDIM / 64), 256, 0, stream>>>(Wq, Wk, Wv, wqkv);
  trans_lmw<<<(VOC / 64) * (EDIM / 64), 256, 0, stream>>>(lmW, lmWt);
  // QKV proj: M=4096, N=3072, K=1024 -> 12*32 = 384 blocks
  gemm128<false, false><<<(QKVN / 256) * (MROWS / 128), 512, 0, stream>>>(
      x, wqkv, nullptr, qkv, nullptr, QKVN, EDIM);
  attn_kernel<<<NB * NH * (TSEQ / 64), 256, 0, stream>>>(qkv, att);
  // LM head: M=4096, N=32000, K=1024 -> 125*32 = 4000 blocks, wave tile 128x64
  gemm128w<true, true><<<(VOC / 256) * (MROWS / 128), 256, 0, stream>>>(
      att, lmWt, out, nullptr, lmb, VOC, EDIM);
}